// Round 4
// baseline (838.215 us; speedup 1.0000x reference)
//
#include <hip/hip_runtime.h>
#include <stdint.h>

// Problem dims
#define NB  256
#define NT  100
#define NIN 128
#define NH  1024
#define NOUT 35
#define MT  112             // time rows padded to 7*16 for MFMA M-tiles

// d_out float offsets
#define O_SPK2 26214400ull
#define O_SPK3 52428800ull
#define O_SPK4 78643200ull
#define O_MEM4 79539200ull

// ws byte offsets
#define WS_SPK0 0ull                  // 256*112*1024 = 29360128 (spike bytes [b][t][k])
#define WS_SPK1 29360128ull           // second ping-pong buffer
#define WS_K2B  58720256ull           // 1024*1024 i8
#define WS_K3B  59768832ull           // 1024*1024 i8
#define WS_K4B  60817408ull           // 48*1024 i8 (rows 35..47 zero)
#define WS_Q1T  60866560ull           // 128*1024 f32 = 524288
#define WS_N1   61390848ull           // 25600 u32
#define WS_N2   61493248ull
#define WS_N3   61595648ull
// end 61698048 (~59 MB)

#define S2C ((float)((1.0 - 0.001) / 15.0))
#define S1C ((float)(1.0 / 15.0))

typedef int v4i __attribute__((ext_vector_type(4)));

__device__ __forceinline__ void async16(const void* g, void* l) {
  __builtin_amdgcn_global_load_lds((const __attribute__((address_space(1))) uint32_t*)g,
                                   (__attribute__((address_space(3))) uint32_t*)l, 16, 0, 0);
}

__device__ __forceinline__ uint8_t qk(float w) {   // k-index 0..15 for (0.001,1.0) quant
  float wc = fminf(fmaxf(w, 0.001f), 1.0f);
  return (uint8_t)(int)rintf((wc - 0.001f) / S2C);
}

// ------------------------------------------------------------------
// K1: weight quantization (coalesced) + q1T f32 + zero n1..n3
// ------------------------------------------------------------------
__global__ void k_prep(const float* __restrict__ w1, const float* __restrict__ w2,
                       const float* __restrict__ w3, const float* __restrict__ w4,
                       uint8_t* __restrict__ ws)
{
  long long id = (long long)blockIdx.x * 256 + threadIdx.x;
  if (id < 1048576) { ws[WS_K2B + id] = qk(w2[id]); return; }
  id -= 1048576;
  if (id < 1048576) { ws[WS_K3B + id] = qk(w3[id]); return; }
  id -= 1048576;
  if (id < 49152) {                        // k4b[j][i], 48 rows, j<35 real else 0
    int j = (int)(id >> 10), i = (int)(id & 1023);
    ws[WS_K4B + id] = (j < NOUT) ? qk(w4[(size_t)j * 1024 + i]) : (uint8_t)0;
    return;
  }
  id -= 49152;
  if (id < 131072) {                       // q1T[i*1024+j] = fake_quant(w1[j][i]) fp32
    int i = (int)(id >> 10), j = (int)(id & 1023);
    float wv = w1[(size_t)j * 128 + i];
    float wc = fminf(fmaxf(wv, -0.5f), 0.5f);
    float q = rintf((wc + 0.5f) / S1C) * S1C - 0.5f;
    ((float*)(ws + WS_Q1T))[id] = q;
    return;
  }
  id -= 131072;
  if (id < 76800) ((uint32_t*)(ws + WS_N1))[id] = 0;   // zero n1,n2,n3 (contiguous)
}

// ------------------------------------------------------------------
// K2: fused layer 1. Block = (b, jb of 128 j). fp32 GEMM M=112(t) x
//     N=128 x K=128 with thread-cyclic 7x8 register tile, C->LDS,
//     in-LDS membrane scan -> spk1 floats + spike bytes + n1.
// ------------------------------------------------------------------
__global__ __launch_bounds__(256) void k_l1(const float* __restrict__ x,
                                            uint8_t* __restrict__ ws,
                                            float* __restrict__ out)
{
  __shared__ float lds[128 * 116 + 128 * 128];   // xsT | qs ; cbuf overlays xsT
  float* xsT = lds;                  // [k][t] stride 116
  float* qs  = lds + 128 * 116;      // [k][j] stride 128
  float* cbuf = lds;                 // [t][j] stride 132 (112*132=14784 <= 14848)
  const float* q1T = (const float*)(ws + WS_Q1T);
  uint8_t* spk0 = ws + WS_SPK0;
  uint32_t* n1 = (uint32_t*)(ws + WS_N1);

  const int b = blockIdx.x, jb = blockIdx.y;
  const int tid = threadIdx.x;
  const int ty = tid >> 4, tx = tid & 15;

  // stage x[b] (100x128, /15) transposed into xsT[k][t]
  #pragma unroll
  for (int it = 0; it < 50; ++it) {
    int e = tid + it * 256;            // 12800 elems
    int t = e >> 7, i = e & 127;
    xsT[i * 116 + t] = x[(size_t)b * 12800 + e] / 15.0f;
  }
  // stage q1T slice [128][128]
  #pragma unroll
  for (int it = 0; it < 32; ++it) {
    int e4 = (tid + it * 256) * 4;     // 32768 floats
    int i = e4 >> 7, j = e4 & 127;
    *(float4*)&qs[i * 128 + j] = *(const float4*)&q1T[(size_t)i * 1024 + jb * 128 + j];
  }
  __syncthreads();

  float acc[7][8];
  #pragma unroll
  for (int i = 0; i < 7; ++i)
    #pragma unroll
    for (int j = 0; j < 8; ++j) acc[i][j] = 0.f;

  #pragma unroll 4
  for (int k = 0; k < 128; ++k) {
    float a[7], q[8];
    #pragma unroll
    for (int i = 0; i < 7; ++i) a[i] = xsT[k * 116 + ty + 16 * i];
    #pragma unroll
    for (int j = 0; j < 8; ++j) q[j] = qs[k * 128 + tx + 16 * j];
    #pragma unroll
    for (int i = 0; i < 7; ++i)
      #pragma unroll
      for (int j = 0; j < 8; ++j)
        acc[i][j] = fmaf(a[i], q[j], acc[i][j]);
  }
  __syncthreads();
  // C -> LDS [t][j]
  #pragma unroll
  for (int i = 0; i < 7; ++i)
    #pragma unroll
    for (int j = 0; j < 8; ++j)
      cbuf[(ty + 16 * i) * 132 + tx + 16 * j] = acc[i][j];
  __syncthreads();

  if (tid < 128) {
    int j = tid;
    float m = 0.f;
    for (int t = 0; t < NT; ++t) {
      float c = cbuf[t * 132 + j];
      float rst = m > 1.0f ? 1.0f : 0.0f;
      m = fmaf(0.9f, m, c) - rst;
      bool sp = (m - 1.0f) > 0.0f;
      out[((size_t)t * NB + b) * NH + jb * 128 + j] = sp ? 1.0f : 0.0f;
      spk0[((size_t)b * MT + t) * 1024 + jb * 128 + j] = sp ? 1 : 0;
      unsigned long long bal = __ballot(sp);
      if ((tid & 63) == 0) atomicAdd((unsigned int*)&n1[t * NB + b], (unsigned)__popcll(bal));
    }
    for (int t = NT; t < MT; ++t)
      spk0[((size_t)b * MT + t) * 1024 + jb * 128 + j] = 0;
  }
}

// ------------------------------------------------------------------
// K3: fused hidden layer (2 and 3). Block = (b, jb of 128 j).
//     i8 MFMA GEMM M=112(t) x N=128 x K=1024, C(u16 K-values)->LDS,
//     in-LDS scan -> spk floats + next spike bytes + n_out.
// ------------------------------------------------------------------
__global__ __launch_bounds__(256) void k_l23(const uint8_t* __restrict__ Aspk,
                                             const uint8_t* __restrict__ Bq,
                                             const uint32_t* __restrict__ nprev,
                                             uint32_t* __restrict__ nout,
                                             float beta,
                                             float* __restrict__ outF,
                                             uint8_t* __restrict__ spkOut)
{
  __shared__ uint8_t lds[61440];     // sA 28KB | sB 32KB ; cbuf overlays sA(+)
  __shared__ uint32_t nbuf[112];
  uint8_t* sA = lds;
  uint8_t* sB = lds + 28672;
  uint16_t* cbuf = (uint16_t*)lds;   // [112][132] u16 = 29568 B

  const int b = blockIdx.x, jb = blockIdx.y;
  const int tid = threadIdx.x, lane = tid & 63, wave = tid >> 6;
  const int lm = lane & 15, lk = lane >> 4;

  if (tid < NT) nbuf[tid] = nprev[tid * NB + b];

  const uint8_t* Ab = Aspk + (size_t)b * MT * 1024;
  const uint8_t* Bb = Bq + (size_t)jb * 128 * 1024;

  v4i acc[7][2];
  #pragma unroll
  for (int m = 0; m < 7; ++m)
    #pragma unroll
    for (int n = 0; n < 2; ++n) { acc[m][n][0]=0; acc[m][n][1]=0; acc[m][n][2]=0; acc[m][n][3]=0; }

  for (int kk = 0; kk < 1024; kk += 256) {
    __syncthreads();
    #pragma unroll
    for (int q = 0; q < 15; ++q) {
      int cid = wave * 15 + q;               // 0..59
      if (cid < 28) {                        // A chunk: mt 0..6, ks 0..3
        int mt = cid >> 2, ks = cid & 3;
        async16(Ab + (size_t)(mt * 16 + lm) * 1024 + kk + ks * 64 + lk * 16, sA + cid * 1024);
      } else if (cid < 60) {                 // B chunk: nt 0..7, ks 0..3
        int c2 = cid - 28, nt = c2 >> 2, ks = c2 & 3;
        async16(Bb + (size_t)(nt * 16 + lm) * 1024 + kk + ks * 64 + lk * 16, sB + c2 * 1024);
      }
    }
    __syncthreads();
    #pragma unroll
    for (int ks = 0; ks < 4; ++ks) {
      v4i bv0 = *(const v4i*)(sB + (size_t)((2 * wave) * 4 + ks) * 1024 + lane * 16);
      v4i bv1 = *(const v4i*)(sB + (size_t)((2 * wave + 1) * 4 + ks) * 1024 + lane * 16);
      #pragma unroll
      for (int m = 0; m < 7; ++m) {
        v4i av = *(const v4i*)(sA + (size_t)(m * 4 + ks) * 1024 + lane * 16);
        acc[m][0] = __builtin_amdgcn_mfma_i32_16x16x64_i8(av, bv0, acc[m][0], 0, 0, 0);
        acc[m][1] = __builtin_amdgcn_mfma_i32_16x16x64_i8(av, bv1, acc[m][1], 0, 0, 0);
      }
    }
  }
  __syncthreads();
  #pragma unroll
  for (int m = 0; m < 7; ++m)
    #pragma unroll
    for (int n = 0; n < 2; ++n)
      #pragma unroll
      for (int r = 0; r < 4; ++r) {
        int row = m * 16 + lk * 4 + r;
        int col = (2 * wave + n) * 16 + lm;
        cbuf[row * 132 + col] = (uint16_t)acc[m][n][r];
      }
  __syncthreads();

  if (tid < 128) {
    int j = tid;
    float m = 0.f;
    for (int t = 0; t < NT; ++t) {
      int kv = cbuf[t * 132 + j];
      float cur = fmaf(S2C, (float)kv, 0.001f * (float)nbuf[t]);
      float rst = m > 1.0f ? 1.0f : 0.0f;
      m = fmaf(beta, m, cur) - rst;
      bool sp = (m - 1.0f) > 0.0f;
      outF[((size_t)t * NB + b) * NH + jb * 128 + j] = sp ? 1.0f : 0.0f;
      spkOut[((size_t)b * MT + t) * 1024 + jb * 128 + j] = sp ? 1 : 0;
      unsigned long long bal = __ballot(sp);
      if ((tid & 63) == 0) atomicAdd((unsigned int*)&nout[t * NB + b], (unsigned)__popcll(bal));
    }
    for (int t = NT; t < MT; ++t)
      spkOut[((size_t)b * MT + t) * 1024 + jb * 128 + j] = 0;
  }
}

// ------------------------------------------------------------------
// K4: fused layer 4 (zero-reset). Block = b. i8 MFMA GEMM M=112 x
//     N=48(pad of 35) x K=1024 + in-LDS scan -> spk4, mem4.
// ------------------------------------------------------------------
__global__ __launch_bounds__(256) void k_l4(const uint8_t* __restrict__ Aspk,
                                            const uint8_t* __restrict__ ws,
                                            float* __restrict__ out)
{
  __shared__ uint8_t lds[40960];     // sA 28KB | sB 12KB ; cbuf overlays sA
  __shared__ uint32_t nbuf[112];
  uint8_t* sA = lds;
  uint8_t* sB = lds + 28672;
  uint16_t* cbuf = (uint16_t*)lds;   // [112][52] u16 = 11648 B

  const int b = blockIdx.x;
  const int tid = threadIdx.x, lane = tid & 63, wave = tid >> 6;
  const int lm = lane & 15, lk = lane >> 4;
  const uint8_t* Bq = ws + WS_K4B;
  const uint32_t* n3 = (const uint32_t*)(ws + WS_N3);

  if (tid < NT) nbuf[tid] = n3[tid * NB + b];

  const uint8_t* Ab = Aspk + (size_t)b * MT * 1024;

  v4i acc[7];
  #pragma unroll
  for (int m = 0; m < 7; ++m) { acc[m][0]=0; acc[m][1]=0; acc[m][2]=0; acc[m][3]=0; }

  for (int kk = 0; kk < 1024; kk += 256) {
    __syncthreads();
    #pragma unroll
    for (int q = 0; q < 10; ++q) {
      int cid = wave * 10 + q;               // 0..39
      if (cid < 28) {
        int mt = cid >> 2, ks = cid & 3;
        async16(Ab + (size_t)(mt * 16 + lm) * 1024 + kk + ks * 64 + lk * 16, sA + cid * 1024);
      } else if (cid < 40) {
        int c2 = cid - 28, nt = c2 >> 2, ks = c2 & 3;
        async16(Bq + (size_t)(nt * 16 + lm) * 1024 + kk + ks * 64 + lk * 16, sB + c2 * 1024);
      }
    }
    __syncthreads();
    if (wave < 3) {
      #pragma unroll
      for (int ks = 0; ks < 4; ++ks) {
        v4i bv = *(const v4i*)(sB + (size_t)(wave * 4 + ks) * 1024 + lane * 16);
        #pragma unroll
        for (int m = 0; m < 7; ++m) {
          v4i av = *(const v4i*)(sA + (size_t)(m * 4 + ks) * 1024 + lane * 16);
          acc[m] = __builtin_amdgcn_mfma_i32_16x16x64_i8(av, bv, acc[m], 0, 0, 0);
        }
      }
    }
  }
  __syncthreads();
  if (wave < 3) {
    #pragma unroll
    for (int m = 0; m < 7; ++m)
      #pragma unroll
      for (int r = 0; r < 4; ++r) {
        int row = m * 16 + lk * 4 + r;
        int col = wave * 16 + lm;
        cbuf[row * 52 + col] = (uint16_t)acc[m][r];
      }
  }
  __syncthreads();

  if (tid < NOUT) {
    int j = tid;
    float m = 0.f;
    for (int t = 0; t < NT; ++t) {
      int kv = cbuf[t * 52 + j];
      float cur = fmaf(S2C, (float)kv, 0.001f * (float)nbuf[t]);
      float rst = m > 1.0f ? 1.0f : 0.0f;
      float bsv = fmaf(0.95f, m, cur);
      m = (rst > 0.0f) ? 0.0f : bsv;
      size_t rowO = ((size_t)t * NB + b) * NOUT + j;
      out[O_SPK4 + rowO] = ((m - 1.0f) > 0.0f) ? 1.0f : 0.0f;
      out[O_MEM4 + rowO] = m;
    }
  }
}

extern "C" void kernel_launch(void* const* d_in, const int* in_sizes, int n_in,
                              void* d_out, int out_size, void* d_ws, size_t ws_size,
                              hipStream_t stream)
{
  const float* x  = (const float*)d_in[0];
  const float* w1 = (const float*)d_in[1];
  const float* w2 = (const float*)d_in[2];
  const float* w3 = (const float*)d_in[3];
  const float* w4 = (const float*)d_in[4];
  float* out = (float*)d_out;
  uint8_t* ws = (uint8_t*)d_ws;

  uint8_t* SPK0 = ws + WS_SPK0;
  uint8_t* SPK1 = ws + WS_SPK1;
  uint32_t* N1 = (uint32_t*)(ws + WS_N1);
  uint32_t* N2 = (uint32_t*)(ws + WS_N2);
  uint32_t* N3 = (uint32_t*)(ws + WS_N3);

  hipLaunchKernelGGL(k_prep, dim3(9196), dim3(256), 0, stream, w1, w2, w3, w4, ws);
  hipLaunchKernelGGL(k_l1,  dim3(256, 8), dim3(256), 0, stream, x, ws, out);
  hipLaunchKernelGGL(k_l23, dim3(256, 8), dim3(256), 0, stream,
                     SPK0, ws + WS_K2B, N1, N2, 0.85f, out + O_SPK2, SPK1);
  hipLaunchKernelGGL(k_l23, dim3(256, 8), dim3(256), 0, stream,
                     SPK1, ws + WS_K3B, N2, N3, 0.8f, out + O_SPK3, SPK0);
  hipLaunchKernelGGL(k_l4,  dim3(256), dim3(256), 0, stream, SPK0, ws, out);
}

// Round 5
// 727.475 us; speedup vs baseline: 1.1522x; 1.1522x over previous
//
#include <hip/hip_runtime.h>
#include <stdint.h>

// Problem dims
#define NB  256
#define NT  100
#define NIN 128
#define NH  1024
#define NOUT 35
#define MT  112             // time rows padded to 7*16 for MFMA M-tiles

// d_out float offsets
#define O_SPK2 26214400ull
#define O_SPK3 52428800ull
#define O_SPK4 78643200ull
#define O_MEM4 79539200ull

// ws byte offsets
#define WS_SPK0 0ull                  // 256*112*1024 = 29360128 (spike bytes [b][t][k])
#define WS_SPK1 29360128ull           // second ping-pong buffer
#define WS_K2B  58720256ull           // 1024*1024 i8
#define WS_K3B  59768832ull           // 1024*1024 i8
#define WS_K4B  60817408ull           // 48*1024 i8 (rows 35..47 zero)
#define WS_Q1T  60866560ull           // 128*1024 f32 = 524288
#define WS_N1   61390848ull           // 25600 u32
#define WS_N2   61493248ull
#define WS_N3   61595648ull
// end 61698048 (~59 MB)

#define S2C ((float)((1.0 - 0.001) / 15.0))
#define S1C ((float)(1.0 / 15.0))

typedef int v4i __attribute__((ext_vector_type(4)));

__device__ __forceinline__ void async16(const void* g, void* l) {
  __builtin_amdgcn_global_load_lds((const __attribute__((address_space(1))) uint32_t*)g,
                                   (__attribute__((address_space(3))) uint32_t*)l, 16, 0, 0);
}

__device__ __forceinline__ uint8_t qk(float w) {   // k-index 0..15 for (0.001,1.0) quant
  float wc = fminf(fmaxf(w, 0.001f), 1.0f);
  return (uint8_t)(int)rintf((wc - 0.001f) / S2C);
}

// ------------------------------------------------------------------
// K1: weight quantization (coalesced) + q1T f32 + zero n1..n3
// ------------------------------------------------------------------
__global__ void k_prep(const float* __restrict__ w1, const float* __restrict__ w2,
                       const float* __restrict__ w3, const float* __restrict__ w4,
                       uint8_t* __restrict__ ws)
{
  long long id = (long long)blockIdx.x * 256 + threadIdx.x;
  if (id < 1048576) { ws[WS_K2B + id] = qk(w2[id]); return; }
  id -= 1048576;
  if (id < 1048576) { ws[WS_K3B + id] = qk(w3[id]); return; }
  id -= 1048576;
  if (id < 49152) {                        // k4b[j][i], 48 rows, j<35 real else 0
    int j = (int)(id >> 10), i = (int)(id & 1023);
    ws[WS_K4B + id] = (j < NOUT) ? qk(w4[(size_t)j * 1024 + i]) : (uint8_t)0;
    return;
  }
  id -= 49152;
  if (id < 131072) {                       // q1T[i*1024+j] = fake_quant(w1[j][i]) fp32
    int i = (int)(id >> 10), j = (int)(id & 1023);
    float wv = w1[(size_t)j * 128 + i];
    float wc = fminf(fmaxf(wv, -0.5f), 0.5f);
    float q = rintf((wc + 0.5f) / S1C) * S1C - 0.5f;
    ((float*)(ws + WS_Q1T))[id] = q;
    return;
  }
  id -= 131072;
  if (id < 76800) ((uint32_t*)(ws + WS_N1))[id] = 0;   // zero n1,n2,n3 (contiguous)
}

// ------------------------------------------------------------------
// K2: cur1[(t*256+b)][j] = dot(x[b,t,:]/15, q1T[:,j]) fp32, into spk1
//     output region (overwritten in place by k_scan1).
//     64 rows x 256 cols per block, per-thread 16x4 register tile.
// ------------------------------------------------------------------
__global__ __launch_bounds__(256) void k_cur1(const float* __restrict__ x,
                                              const uint8_t* __restrict__ ws,
                                              float* __restrict__ out)
{
  __shared__ float xsT[128 * 68];   // [i][r], padded stride 68
  __shared__ float qch[16 * 256];   // [ii][j] chunk of q1T
  const float* q1T = (const float*)(ws + WS_Q1T);
  const int tid = threadIdx.x;
  const int rb = blockIdx.x >> 2, cb = blockIdx.x & 3;
  const int t = rb >> 2, b0 = (rb & 3) * 64;     // rows rb*64.. = (t*256 + b0 + r)
  const int jI = tid & 63, rI = tid >> 6;
  const int j4 = jI * 4, r16 = rI * 16;

  #pragma unroll
  for (int k = 0; k < 32; ++k) {
    int e = tid + k * 256;
    int r = e >> 7, i = e & 127;
    xsT[i * 68 + r] = x[((size_t)(b0 + r) * NT + t) * NIN + i] / 15.0f;
  }
  float acc[16][4];
  #pragma unroll
  for (int d = 0; d < 16; ++d) { acc[d][0]=0.f; acc[d][1]=0.f; acc[d][2]=0.f; acc[d][3]=0.f; }
  for (int ic = 0; ic < 8; ++ic) {
    __syncthreads();
    #pragma unroll
    for (int k = 0; k < 16; ++k) {
      int e = tid + k * 256;
      int ii = e >> 8, j = e & 255;
      qch[ii * 256 + j] = q1T[((size_t)(ic * 16 + ii) << 10) + cb * 256 + j];
    }
    __syncthreads();
    #pragma unroll
    for (int ii = 0; ii < 16; ++ii) {
      int i = ic * 16 + ii;
      const float4 q  = *(const float4*)&qch[ii * 256 + j4];
      const float4 xa = *(const float4*)&xsT[i * 68 + r16];
      const float4 xb = *(const float4*)&xsT[i * 68 + r16 + 4];
      const float4 xc = *(const float4*)&xsT[i * 68 + r16 + 8];
      const float4 xd = *(const float4*)&xsT[i * 68 + r16 + 12];
      float xr[16];
      xr[0]=xa.x; xr[1]=xa.y; xr[2]=xa.z; xr[3]=xa.w;
      xr[4]=xb.x; xr[5]=xb.y; xr[6]=xb.z; xr[7]=xb.w;
      xr[8]=xc.x; xr[9]=xc.y; xr[10]=xc.z; xr[11]=xc.w;
      xr[12]=xd.x; xr[13]=xd.y; xr[14]=xd.z; xr[15]=xd.w;
      #pragma unroll
      for (int d = 0; d < 16; ++d) {
        acc[d][0] = fmaf(xr[d], q.x, acc[d][0]);
        acc[d][1] = fmaf(xr[d], q.y, acc[d][1]);
        acc[d][2] = fmaf(xr[d], q.z, acc[d][2]);
        acc[d][3] = fmaf(xr[d], q.w, acc[d][3]);
      }
    }
  }
  #pragma unroll
  for (int d = 0; d < 16; ++d) {
    float4 v = make_float4(acc[d][0], acc[d][1], acc[d][2], acc[d][3]);
    *(float4*)&out[((size_t)rb * 64 + r16 + d) * 1024 + cb * 256 + j4] = v;
  }
}

// ------------------------------------------------------------------
// K3: layer-1 membrane scan: cur1 (in out) -> spk1 floats (in place)
//     + spike bytes in [b][MT][k] layout (+pad zeros) + n1 counts
// ------------------------------------------------------------------
__global__ __launch_bounds__(256) void k_scan1(uint8_t* __restrict__ ws, float* __restrict__ out)
{
  const int tid = threadIdx.x;
  const int b = blockIdx.x >> 2;
  const int j = (blockIdx.x & 3) * 256 + tid;
  uint8_t* spk0 = ws + WS_SPK0;
  uint32_t* n1 = (uint32_t*)(ws + WS_N1);
  const size_t stride = (size_t)NB * NH;
  size_t idx = (size_t)b * NH + j;
  size_t sidx = (size_t)b * MT * 1024 + j;
  float m = 0.f;
  float c = out[idx];
  for (int t = 0; t < NT; ++t) {
    float cn = (t + 1 < NT) ? out[idx + stride] : 0.f;
    float rst = m > 1.0f ? 1.0f : 0.0f;
    m = fmaf(0.9f, m, c) - rst;
    bool sp = (m - 1.0f) > 0.0f;
    out[idx] = sp ? 1.0f : 0.0f;
    spk0[sidx] = sp ? 1 : 0;
    unsigned long long bal = __ballot(sp);
    if ((tid & 63) == 0) atomicAdd((unsigned int*)&n1[t * NB + b], (unsigned)__popcll(bal));
    idx += stride; sidx += 1024; c = cn;
  }
  for (int t = NT; t < MT; ++t) { spk0[sidx] = 0; sidx += 1024; }
}

// ------------------------------------------------------------------
// K4: fused hidden layer (2 and 3). Block = (b, jb of 128 j).
//     i8 MFMA GEMM M=112(t) x N=128 x K=1024, C(u16 K-values)->LDS,
//     in-LDS scan -> spk floats + next spike bytes + n_out.
// ------------------------------------------------------------------
__global__ __launch_bounds__(256) void k_l23(const uint8_t* __restrict__ Aspk,
                                             const uint8_t* __restrict__ Bq,
                                             const uint32_t* __restrict__ nprev,
                                             uint32_t* __restrict__ nout,
                                             float beta,
                                             float* __restrict__ outF,
                                             uint8_t* __restrict__ spkOut)
{
  __shared__ uint8_t lds[61440];     // sA 28KB | sB 32KB ; cbuf overlays sA(+)
  __shared__ uint32_t nbuf[112];
  uint8_t* sA = lds;
  uint8_t* sB = lds + 28672;
  uint16_t* cbuf = (uint16_t*)lds;   // [112][132] u16 = 29568 B

  const int b = blockIdx.x, jb = blockIdx.y;
  const int tid = threadIdx.x, lane = tid & 63, wave = tid >> 6;
  const int lm = lane & 15, lk = lane >> 4;

  if (tid < NT) nbuf[tid] = nprev[tid * NB + b];

  const uint8_t* Ab = Aspk + (size_t)b * MT * 1024;
  const uint8_t* Bb = Bq + (size_t)jb * 128 * 1024;

  v4i acc[7][2];
  #pragma unroll
  for (int m = 0; m < 7; ++m)
    #pragma unroll
    for (int n = 0; n < 2; ++n) { acc[m][n][0]=0; acc[m][n][1]=0; acc[m][n][2]=0; acc[m][n][3]=0; }

  for (int kk = 0; kk < 1024; kk += 256) {
    __syncthreads();
    #pragma unroll
    for (int q = 0; q < 15; ++q) {
      int cid = wave * 15 + q;               // 0..59
      if (cid < 28) {                        // A chunk: mt 0..6, ks 0..3
        int mt = cid >> 2, ks = cid & 3;
        async16(Ab + (size_t)(mt * 16 + lm) * 1024 + kk + ks * 64 + lk * 16, sA + cid * 1024);
      } else if (cid < 60) {                 // B chunk: nt 0..7, ks 0..3
        int c2 = cid - 28, nt = c2 >> 2, ks = c2 & 3;
        async16(Bb + (size_t)(nt * 16 + lm) * 1024 + kk + ks * 64 + lk * 16, sB + c2 * 1024);
      }
    }
    __syncthreads();
    #pragma unroll
    for (int ks = 0; ks < 4; ++ks) {
      v4i bv0 = *(const v4i*)(sB + (size_t)((2 * wave) * 4 + ks) * 1024 + lane * 16);
      v4i bv1 = *(const v4i*)(sB + (size_t)((2 * wave + 1) * 4 + ks) * 1024 + lane * 16);
      #pragma unroll
      for (int m = 0; m < 7; ++m) {
        v4i av = *(const v4i*)(sA + (size_t)(m * 4 + ks) * 1024 + lane * 16);
        acc[m][0] = __builtin_amdgcn_mfma_i32_16x16x64_i8(av, bv0, acc[m][0], 0, 0, 0);
        acc[m][1] = __builtin_amdgcn_mfma_i32_16x16x64_i8(av, bv1, acc[m][1], 0, 0, 0);
      }
    }
  }
  __syncthreads();
  #pragma unroll
  for (int m = 0; m < 7; ++m)
    #pragma unroll
    for (int n = 0; n < 2; ++n)
      #pragma unroll
      for (int r = 0; r < 4; ++r) {
        int row = m * 16 + lk * 4 + r;
        int col = (2 * wave + n) * 16 + lm;
        cbuf[row * 132 + col] = (uint16_t)acc[m][n][r];
      }
  __syncthreads();

  if (tid < 128) {
    int j = tid;
    float m = 0.f;
    for (int t = 0; t < NT; ++t) {
      int kv = cbuf[t * 132 + j];
      float cur = fmaf(S2C, (float)kv, 0.001f * (float)nbuf[t]);
      float rst = m > 1.0f ? 1.0f : 0.0f;
      m = fmaf(beta, m, cur) - rst;
      bool sp = (m - 1.0f) > 0.0f;
      outF[((size_t)t * NB + b) * NH + jb * 128 + j] = sp ? 1.0f : 0.0f;
      spkOut[((size_t)b * MT + t) * 1024 + jb * 128 + j] = sp ? 1 : 0;
      unsigned long long bal = __ballot(sp);
      if ((tid & 63) == 0) atomicAdd((unsigned int*)&nout[t * NB + b], (unsigned)__popcll(bal));
    }
    for (int t = NT; t < MT; ++t)
      spkOut[((size_t)b * MT + t) * 1024 + jb * 128 + j] = 0;
  }
}

// ------------------------------------------------------------------
// K5: fused layer 4 (zero-reset). Block = b. i8 MFMA GEMM M=112 x
//     N=48(pad of 35) x K=1024 + in-LDS scan -> spk4, mem4.
// ------------------------------------------------------------------
__global__ __launch_bounds__(256) void k_l4(const uint8_t* __restrict__ Aspk,
                                            const uint8_t* __restrict__ ws,
                                            float* __restrict__ out)
{
  __shared__ uint8_t lds[40960];     // sA 28KB | sB 12KB ; cbuf overlays sA
  __shared__ uint32_t nbuf[112];
  uint8_t* sA = lds;
  uint8_t* sB = lds + 28672;
  uint16_t* cbuf = (uint16_t*)lds;   // [112][52] u16 = 11648 B

  const int b = blockIdx.x;
  const int tid = threadIdx.x, lane = tid & 63, wave = tid >> 6;
  const int lm = lane & 15, lk = lane >> 4;
  const uint8_t* Bq = ws + WS_K4B;
  const uint32_t* n3 = (const uint32_t*)(ws + WS_N3);

  if (tid < NT) nbuf[tid] = n3[tid * NB + b];

  const uint8_t* Ab = Aspk + (size_t)b * MT * 1024;

  v4i acc[7];
  #pragma unroll
  for (int m = 0; m < 7; ++m) { acc[m][0]=0; acc[m][1]=0; acc[m][2]=0; acc[m][3]=0; }

  for (int kk = 0; kk < 1024; kk += 256) {
    __syncthreads();
    #pragma unroll
    for (int q = 0; q < 10; ++q) {
      int cid = wave * 10 + q;               // 0..39
      if (cid < 28) {
        int mt = cid >> 2, ks = cid & 3;
        async16(Ab + (size_t)(mt * 16 + lm) * 1024 + kk + ks * 64 + lk * 16, sA + cid * 1024);
      } else if (cid < 40) {
        int c2 = cid - 28, nt = c2 >> 2, ks = c2 & 3;
        async16(Bq + (size_t)(nt * 16 + lm) * 1024 + kk + ks * 64 + lk * 16, sB + c2 * 1024);
      }
    }
    __syncthreads();
    if (wave < 3) {
      #pragma unroll
      for (int ks = 0; ks < 4; ++ks) {
        v4i bv = *(const v4i*)(sB + (size_t)(wave * 4 + ks) * 1024 + lane * 16);
        #pragma unroll
        for (int m = 0; m < 7; ++m) {
          v4i av = *(const v4i*)(sA + (size_t)(m * 4 + ks) * 1024 + lane * 16);
          acc[m] = __builtin_amdgcn_mfma_i32_16x16x64_i8(av, bv, acc[m], 0, 0, 0);
        }
      }
    }
  }
  __syncthreads();
  if (wave < 3) {
    #pragma unroll
    for (int m = 0; m < 7; ++m)
      #pragma unroll
      for (int r = 0; r < 4; ++r) {
        int row = m * 16 + lk * 4 + r;
        int col = wave * 16 + lm;
        cbuf[row * 52 + col] = (uint16_t)acc[m][r];
      }
  }
  __syncthreads();

  if (tid < NOUT) {
    int j = tid;
    float m = 0.f;
    for (int t = 0; t < NT; ++t) {
      int kv = cbuf[t * 52 + j];
      float cur = fmaf(S2C, (float)kv, 0.001f * (float)nbuf[t]);
      float rst = m > 1.0f ? 1.0f : 0.0f;
      float bsv = fmaf(0.95f, m, cur);
      m = (rst > 0.0f) ? 0.0f : bsv;
      size_t rowO = ((size_t)t * NB + b) * NOUT + j;
      out[O_SPK4 + rowO] = ((m - 1.0f) > 0.0f) ? 1.0f : 0.0f;
      out[O_MEM4 + rowO] = m;
    }
  }
}

extern "C" void kernel_launch(void* const* d_in, const int* in_sizes, int n_in,
                              void* d_out, int out_size, void* d_ws, size_t ws_size,
                              hipStream_t stream)
{
  const float* x  = (const float*)d_in[0];
  const float* w1 = (const float*)d_in[1];
  const float* w2 = (const float*)d_in[2];
  const float* w3 = (const float*)d_in[3];
  const float* w4 = (const float*)d_in[4];
  float* out = (float*)d_out;
  uint8_t* ws = (uint8_t*)d_ws;

  uint8_t* SPK0 = ws + WS_SPK0;
  uint8_t* SPK1 = ws + WS_SPK1;
  uint32_t* N1 = (uint32_t*)(ws + WS_N1);
  uint32_t* N2 = (uint32_t*)(ws + WS_N2);
  uint32_t* N3 = (uint32_t*)(ws + WS_N3);

  hipLaunchKernelGGL(k_prep, dim3(9196), dim3(256), 0, stream, w1, w2, w3, w4, ws);
  hipLaunchKernelGGL(k_cur1, dim3(1600), dim3(256), 0, stream, x, ws, out);
  hipLaunchKernelGGL(k_scan1, dim3(1024), dim3(256), 0, stream, ws, out);
  hipLaunchKernelGGL(k_l23, dim3(256, 8), dim3(256), 0, stream,
                     SPK0, ws + WS_K2B, N1, N2, 0.85f, out + O_SPK2, SPK1);
  hipLaunchKernelGGL(k_l23, dim3(256, 8), dim3(256), 0, stream,
                     SPK1, ws + WS_K3B, N2, N3, 0.8f, out + O_SPK3, SPK0);
  hipLaunchKernelGGL(k_l4,  dim3(256), dim3(256), 0, stream, SPK0, ws, out);
}